// Round 9
// baseline (249.165 us; speedup 1.0000x reference)
//
#include <hip/hip_runtime.h>

// MultiHeadedAttention: B=2, S=2048, D=1024, H=16, DH=64.
// fp32 in/out; internal bf16 MFMA pipeline.
// cvt (fp32->bf16) -> QKV bf16 GEMMs -> flash attention (static-max) -> oproj.
// R1: attn 4 blocks/CU, XOR-swizzled LDS, setprio.
// R2: 2-phase double-buffer (one barrier/tile).
// R4: V epilogue via LDS transpose -> 16B stores.
// R5: swapped QK^T + in-register P redistribution (permlane32/16); conflicts=0.
// R6: paired q-tiles REGRESSED (resident-wave starvation) -> reverted.
// R7: fused fp32 reg-staging REGRESSED (scratch spills) -> reverted.
// R8: GEMM core -> 3-buffer depth-2 prefetch, counted vmcnt(4) + raw barrier
//     (qkv 47.8->41.6, at the 2-phase 128^2 structural ceiling ~620 TF).
// R9: attn: V staging DELETED (all waves read the same V rows; direct global
//     reads hit per-XCD L2), K-only 3-buffer depth-2 with counted vmcnt(2).
//     LDS 32->24KB, staging 4->2 loads/wave/tile, one barrier/tile, no drain.

typedef __bf16 bf16x8 __attribute__((ext_vector_type(8)));
typedef __bf16 bf16x4 __attribute__((ext_vector_type(4)));
typedef float  f32x4  __attribute__((ext_vector_type(4)));
typedef int    i32x2  __attribute__((ext_vector_type(2)));
typedef int    i32x4  __attribute__((ext_vector_type(4)));

#define B_  2
#define S_  2048
#define D_  1024
#define H_  16
#define DH_ 64

#define NEG_ 1.0e30f              // finite "-inf": exp2 -> 0, no inf-inf NaN
#define M2_  5.77078016f          // static softmax max: 4.0 * log2(e)
#define QSCALE_ 0.18033688f       // 1/sqrt(64) * log2(e): scores in log2 domain

#if __has_builtin(__builtin_amdgcn_exp2f)
#define EXP2(x) __builtin_amdgcn_exp2f(x)
#else
#define EXP2(x) __builtin_exp2f(x)
#endif

// ---- async 16B global -> LDS copy (lane l writes lds_base + l*16B) ---------
__device__ __forceinline__ void load_lds16(const __bf16* g, __bf16* lds_base) {
    __builtin_amdgcn_global_load_lds(
        (const __attribute__((address_space(1))) void*)g,
        (__attribute__((address_space(3))) void*)lds_base,
        16, 0, 0);
}

// ---- pack two f32 -> one u32 of 2 bf16 (lo = first) ------------------------
__device__ __forceinline__ int pack_bf16(float lo, float hi) {
    union { int u; __bf16 h[2]; } r;
    r.h[0] = (__bf16)lo; r.h[1] = (__bf16)hi;
    return r.u;
}

// ---- cross-lane half swaps (32-lane and 16-lane rows) ----------------------
__device__ __forceinline__ void p32swap(int& a, int& b, int lane) {
#if __has_builtin(__builtin_amdgcn_permlane32_swap)
    i32x2 r = __builtin_amdgcn_permlane32_swap(a, b, false, false);
    a = r[0]; b = r[1];
#else
    const int addr = ((lane ^ 32) & 63) << 2;
    int ax = __builtin_amdgcn_ds_bpermute(addr, a);
    int bx = __builtin_amdgcn_ds_bpermute(addr, b);
    int na = (lane < 32) ? a : bx;
    int nb = (lane < 32) ? ax : b;
    a = na; b = nb;
#endif
}
__device__ __forceinline__ void p16swap(int& a, int& b, int lane) {
#if __has_builtin(__builtin_amdgcn_permlane16_swap)
    i32x2 r = __builtin_amdgcn_permlane16_swap(a, b, false, false);
    a = r[0]; b = r[1];
#else
    int as = __builtin_amdgcn_ds_swizzle(a, 0x401F);  // lane ^ 16 (in 32-grp)
    int bs = __builtin_amdgcn_ds_swizzle(b, 0x401F);
    const bool odd = (lane >> 4) & 1;
    int na = odd ? bs : a;
    int nb = odd ? b : as;
    a = na; b = nb;
#endif
}

// ---- load 8 consecutive fp32, convert to packed bf16x8 ---------------------
__device__ __forceinline__ bf16x8 cvt8(const float* __restrict__ p) {
    const float4 a = *(const float4*)p;
    const float4 b = *(const float4*)(p + 4);
    bf16x8 r;
    r[0] = (__bf16)a.x; r[1] = (__bf16)a.y; r[2] = (__bf16)a.z; r[3] = (__bf16)a.w;
    r[4] = (__bf16)b.x; r[5] = (__bf16)b.y; r[6] = (__bf16)b.z; r[7] = (__bf16)b.w;
    return r;
}

// ---- fp32 -> bf16 conversion pass: z picks tensor --------------------------
__global__ void cvt_kernel(const float* __restrict__ q, const float* __restrict__ k,
                           const float* __restrict__ v,
                           const float* __restrict__ wq, const float* __restrict__ wk,
                           const float* __restrict__ wv, const float* __restrict__ wo,
                           __bf16* __restrict__ qb, __bf16* __restrict__ kb,
                           __bf16* __restrict__ vb,
                           __bf16* __restrict__ wqb, __bf16* __restrict__ wkb,
                           __bf16* __restrict__ wvb, __bf16* __restrict__ wob) {
    const int z = blockIdx.z;
    const float* src; __bf16* dst; size_t n;
    switch (z) {
        case 0: src = q;  dst = qb;  n = (size_t)B_ * S_ * D_; break;
        case 1: src = k;  dst = kb;  n = (size_t)B_ * S_ * D_; break;
        case 2: src = v;  dst = vb;  n = (size_t)B_ * S_ * D_; break;
        case 3: src = wq; dst = wqb; n = (size_t)D_ * D_; break;
        case 4: src = wk; dst = wkb; n = (size_t)D_ * D_; break;
        case 5: src = wv; dst = wvb; n = (size_t)D_ * D_; break;
        default: src = wo; dst = wob; n = (size_t)D_ * D_; break;
    }
    const size_t i = ((size_t)blockIdx.x * 256 + threadIdx.x) * 8;
    if (i >= n) return;
    *(bf16x8*)(dst + i) = cvt8(src + i);
}

// ---- 128x128 bf16 GEMM core, 3-buffer depth-2 prefetch, counted vmcnt ------
// Y[m,n] = sum_k X[m,k]*W[n,k]. As/Bs are [3][128*32] bf16 (each op 24KB).
// Per K-step: s_waitcnt vmcnt(4) (own stage(k) loads only; stage(k+1) stays
// in flight) -> s_barrier -> issue stage(k+2) -> ds_read + 16 MFMA.
__device__ __forceinline__ void gemm128_bf(const __bf16* __restrict__ X,
                                           const __bf16* __restrict__ W,
                                           int m0, int n0, int K,
                                           __bf16* As, __bf16* Bs,
                                           f32x4 acc[4][4]) {
    const int tid  = threadIdx.x;
    const int wave = tid >> 6, lane = tid & 63;
    const int row  = lane & 15, quad = lane >> 4;
    const int wm   = wave >> 1, wn = wave & 1;
    const int arow = lane >> 2;        // 0..15 row within 16-row chunk
    const int acol = (lane & 3) * 8;   // elem offset within 32-elem row

    const f32x4 fzero = {0.f, 0.f, 0.f, 0.f};
#pragma unroll
    for (int mt = 0; mt < 4; ++mt)
#pragma unroll
        for (int nt = 0; nt < 4; ++nt) acc[mt][nt] = fzero;

    auto stage = [&](int buf, int k0) {   // 4 global_load_lds per wave
#pragma unroll
        for (int c = 0; c < 2; ++c) {
            const int j = wave * 2 + c;  // chunk 0..7, 16 rows each
            load_lds16(X + (size_t)(m0 + j * 16 + arow) * K + k0 + acol,
                       As + buf * 4096 + j * 512);
            load_lds16(W + (size_t)(n0 + j * 16 + arow) * K + k0 + acol,
                       Bs + buf * 4096 + j * 512);
        }
    };

    stage(0, 0);
    if (K > 32) stage(1, 32);
    int cur = 0;
    for (int k0 = 0; k0 < K; k0 += 32) {
        // wait own stage(k) (oldest 4); stage(k+1)'s 4 may stay in flight
        if (k0 + 32 < K) asm volatile("s_waitcnt vmcnt(4)" ::: "memory");
        else             asm volatile("s_waitcnt vmcnt(0)" ::: "memory");
        __builtin_amdgcn_s_barrier();
        __builtin_amdgcn_sched_barrier(0);
        if (k0 + 64 < K) {
            int nxt2 = cur + 2; if (nxt2 >= 3) nxt2 -= 3;
            stage(nxt2, k0 + 64);          // depth-2 prefetch, issued early
        }
        const __bf16* Ab = As + cur * 4096;
        const __bf16* Bb = Bs + cur * 4096;
        bf16x8 af[4], bfv[4];
#pragma unroll
        for (int t = 0; t < 4; ++t) {
            af[t]  = *(const bf16x8*)(Ab + (wm * 64 + t * 16 + row) * 32 + quad * 8);
            bfv[t] = *(const bf16x8*)(Bb + (wn * 64 + t * 16 + row) * 32 + quad * 8);
        }
        __builtin_amdgcn_s_setprio(1);
#pragma unroll
        for (int mt = 0; mt < 4; ++mt)
#pragma unroll
            for (int nt = 0; nt < 4; ++nt)
                acc[mt][nt] = __builtin_amdgcn_mfma_f32_16x16x32_bf16(
                    af[mt], bfv[nt], acc[mt][nt], 0, 0, 0);
        __builtin_amdgcn_s_setprio(0);
        if (++cur >= 3) cur = 0;
    }
    // all staging drained (last iter waited vmcnt(0)); barrier before any
    // LDS reuse by caller epilogues:
    __builtin_amdgcn_s_barrier();
}

// ---- QKV projection (bf16): z selects Q/K/V. Head-split layouts. ----------
__global__ void qkv_kernel(const __bf16* __restrict__ qb, const __bf16* __restrict__ kb,
                           const __bf16* __restrict__ vb,
                           const __bf16* __restrict__ wqb, const __bf16* __restrict__ wkb,
                           const __bf16* __restrict__ wvb,
                           const float* __restrict__ bq, const float* __restrict__ bk,
                           const float* __restrict__ bv,
                           __bf16* __restrict__ q_ws, __bf16* __restrict__ k_ws,
                           __bf16* __restrict__ v_ws) {
    __shared__ __align__(16) __bf16 SMEM[24576];  // 48 KB: 3-buf As|Bs, then V-transpose
    __bf16* As = SMEM;
    __bf16* Bs = SMEM + 12288;

    const int mode = blockIdx.z;
    const __bf16* X    = mode == 0 ? qb : mode == 1 ? kb : vb;
    const __bf16* W    = mode == 0 ? wqb : mode == 1 ? wkb : wvb;
    const float*  bias = mode == 0 ? bq : mode == 1 ? bk : bv;
    const int m0 = blockIdx.y * 128, n0 = blockIdx.x * 128;

    f32x4 acc[4][4];
    gemm128_bf(X, W, m0, n0, D_, As, Bs, acc);

    const int tid = threadIdx.x;
    const int wave = tid >> 6, lane = tid & 63;
    const int row = lane & 15, quad = lane >> 4;
    const int wm = wave >> 1, wn = wave & 1;

    if (mode == 2) {
        // ---- V path: LDS transpose -> vectorized stores along s ----
        __bf16* T = SMEM;              // [nloc][mloc], 16B-chunk XOR swizzle
#pragma unroll
        for (int nt = 0; nt < 4; ++nt) {
            const int nloc = wn * 64 + nt * 16 + row;
            const float bf = bias[n0 + nloc];
#pragma unroll
            for (int mt = 0; mt < 4; ++mt)
#pragma unroll
                for (int r2 = 0; r2 < 4; ++r2) {
                    const int mloc = wm * 64 + mt * 16 + quad * 4 + r2;
                    T[nloc * 128 + ((((mloc >> 3) ^ (nloc & 15)) << 3) | (mloc & 7))] =
                        (__bf16)(acc[mt][nt][r2] + bf);
                }
        }
        __syncthreads();
#pragma unroll
        for (int p = 0; p < 8; ++p) {
            const int nloc = p * 16 + (tid >> 4);
            const int k = tid & 15;    // m-chunk index (8 consecutive s)
            bf16x8 vv = *(const bf16x8*)(T + nloc * 128 + ((k ^ (nloc & 15)) << 3));
            const int n = n0 + nloc;
            const int h = n >> 6, dh = n & 63;
            const int m = m0 + k * 8;
            const int bb = m >> 11, s = m & (S_ - 1);
            *(bf16x8*)(v_ws + (((size_t)bb * H_ + h) * DH_ + dh) * S_ + s) = vv;
        }
        return;
    }

    // ---- Q/K path: direct stores (32B runs per quad, acceptable) ----
#pragma unroll
    for (int nt = 0; nt < 4; ++nt) {
        const int n  = n0 + wn * 64 + nt * 16 + row;
        const float bf = bias[n];
        const int h = n >> 6, dh = n & 63;
#pragma unroll
        for (int mt = 0; mt < 4; ++mt) {
#pragma unroll
            for (int r2 = 0; r2 < 4; ++r2) {
                const int m = m0 + wm * 64 + mt * 16 + quad * 4 + r2;
                const int bb = m >> 11, s = m & (S_ - 1);
                const float val = acc[mt][nt][r2] + bf;
                if (mode == 0)       // Q: (B,H,S,DH), scaled to log2 domain
                    q_ws[(((size_t)bb * H_ + h) * S_ + s) * DH_ + dh] = (__bf16)(val * QSCALE_);
                else                 // K: (B,H,S,DH)
                    k_ws[(((size_t)bb * H_ + h) * S_ + s) * DH_ + dh] = (__bf16)val;
            }
        }
    }
}

// ---- Flash attention. QBLK=64, KVBLK=64. K: 3-buffer depth-2, counted
// vmcnt(2) + raw barrier. V: NO staging -- all waves need the same V rows, so
// each reads its PV A-fragment direct from global (L2-resident via the XCD
// head mapping); issued right after the barrier so QK^T hides the latency.
// Swapped QK^T -> P^T in-register redistribution (R5). LDS 24KB -> 4 WG/CU.
__global__ __launch_bounds__(256, 4)
void attn_kernel(const __bf16* __restrict__ q_ws, const __bf16* __restrict__ k_ws,
                 const __bf16* __restrict__ v_ws, __bf16* __restrict__ att) {
    __shared__ __align__(16) __bf16 Ks[3 * 64 * 64];  // [key][dh], swizzled, 3-buf

    // XCD-aware decode: id%8 = XCD; each XCD owns 4 heads (2MB K/V -> L2-fit).
    const int id = blockIdx.x;
    const int bh = (id & 7) * 4 + ((id >> 3) & 3);
    const int u = id >> 5, ua = u >> 3, uj = u & 7;
    const int qt = ua * 8 + ((ua & 1) ? (7 - uj) : uj);  // balanced involution
    const int tid = threadIdx.x, wave = tid >> 6, lane = tid & 63;
    const int row = lane & 15, quad = lane >> 4;

    const __bf16* Qg = q_ws + ((size_t)bh * S_ + qt * 64 + wave * 16) * DH_;
    const __bf16* Kg = k_ws + (size_t)bh * S_ * DH_;
    const __bf16* Vg = v_ws + (size_t)bh * DH_ * S_;

    // Q fragments (B-operand): q-rows = lane&15, k = ks*32 + quad*8 .. +7
    bf16x8 qf[2];
#pragma unroll
    for (int ks = 0; ks < 2; ++ks)
        qf[ks] = *(const bf16x8*)(Qg + row * DH_ + ks * 32 + quad * 8);

    // all-ones A fragment for row-sum via MFMA: l[q] broadcast over rows
    bf16x8 onesf;
#pragma unroll
    for (int i = 0; i < 8; ++i) onesf[i] = (__bf16)1.0f;

    const f32x4 fzero = {0.f, 0.f, 0.f, 0.f};
    const f32x4 m2init = {-M2_, -M2_, -M2_, -M2_};
    f32x4 oacc[4];   // O^T accumulator: q = lane&15, d = dt*16 + quad*4 + r
    f32x4 lacc = fzero;
#pragma unroll
    for (int dt = 0; dt < 4; ++dt) oacc[dt] = fzero;

    // staging swizzle: LDS dest linear, global source pre-swizzled
    const int srow = lane >> 3;                  // row & 7 within chunk
    const int scol = ((lane & 7) ^ srow) * 8;    // pre-swizzled col (elems)
    const int nkv = qt + 1;

    auto stageK = [&](int buf, int kv) {         // 2 global_load_lds per wave
#pragma unroll
        for (int c = 0; c < 2; ++c) {
            const int ck = wave * 2 + c;         // chunk 0..7, 8 rows each
            load_lds16(Kg + (size_t)(kv * 64 + ck * 8 + srow) * DH_ + scol,
                       Ks + buf * 4096 + ck * 512);
        }
    };

    stageK(0, 0);
    if (nkv > 1) stageK(1, 1);
    int cur = 0;
    for (int kv = 0; kv < nkv; ++kv) {
        // wait own K(kv) (oldest 2); K(kv+1)'s 2 may stay in flight
        if (kv + 1 < nkv) asm volatile("s_waitcnt vmcnt(2)" ::: "memory");
        else              asm volatile("s_waitcnt vmcnt(0)" ::: "memory");
        __builtin_amdgcn_s_barrier();
        __builtin_amdgcn_sched_barrier(0);

        // V fragments for this tile: direct global (L2), issued before K
        // prefetch so the compiler's V-waits keep the K pipeline in flight.
        bf16x8 vreg[2][4];
#pragma unroll
        for (int kc = 0; kc < 2; ++kc)
#pragma unroll
            for (int dt = 0; dt < 4; ++dt)
                vreg[kc][dt] = *(const bf16x8*)(
                    Vg + (size_t)(dt * 16 + row) * S_ + kv * 64 + kc * 32 + quad * 8);

        if (kv + 2 < nkv) {
            int nxt2 = cur + 2; if (nxt2 >= 3) nxt2 -= 3;
            stageK(nxt2, kv + 2);                // depth-2 K prefetch
        }

        const bool diag = (kv == nkv - 1);
        const __bf16* Kb = Ks + cur * 4096;
        const int swz = (row & 7) << 3;          // read-side XOR (elements)

        // process 64 keys in two 32-key slices: QK^T -> exp -> shuffle -> PV
#pragma unroll
        for (int kc = 0; kc < 2; ++kc) {
            // S^T slice = K Q^T: rows = keys (quad*4+r per jn), cols = q rows
            f32x4 s[2];
            s[0] = m2init; s[1] = m2init;        // -M2 folded into C-init
            __builtin_amdgcn_s_setprio(1);
#pragma unroll
            for (int jn = 0; jn < 2; ++jn) {
                const int nt = kc * 2 + jn;
                const int kb = (nt * 16 + row) * 64 + quad * 8;
                bf16x8 kf0 = *(const bf16x8*)(Kb + (kb ^ swz));
                bf16x8 kf1 = *(const bf16x8*)(Kb + ((kb + 32) ^ swz));
                s[jn] = __builtin_amdgcn_mfma_f32_16x16x32_bf16(kf0, qf[0], s[jn], 0, 0, 0);
                s[jn] = __builtin_amdgcn_mfma_f32_16x16x32_bf16(kf1, qf[1], s[jn], 0, 0, 0);
            }
            __builtin_amdgcn_s_setprio(0);

            if (diag) {  // causal mask: key_loc > q_loc -> masked
                const int rloc = wave * 16 + row;          // q row
#pragma unroll
                for (int jn = 0; jn < 2; ++jn)
#pragma unroll
                    for (int r = 0; r < 4; ++r) {
                        const int cloc = kc * 32 + jn * 16 + quad * 4 + r;  // key
                        if (cloc > rloc) s[jn][r] = -NEG_;
                    }
            }

            // p = 2^s (s already has -M2); pack; cross-lane to PV B-fragment
            float p0[4], p1[4];
#pragma unroll
            for (int r = 0; r < 4; ++r) {
                p0[r] = EXP2(s[0][r]);
                p1[r] = EXP2(s[1][r]);
            }
            int a0 = pack_bf16(p0[0], p0[1]), a1 = pack_bf16(p0[2], p0[3]);
            int b0 = pack_bf16(p1[0], p1[1]), b1 = pack_bf16(p1[2], p1[3]);
            p32swap(a0, b0, lane); p16swap(a0, b0, lane);  // -> Bfrag[0], Bfrag[2]
            p32swap(a1, b1, lane); p16swap(a1, b1, lane);  // -> Bfrag[1], Bfrag[3]
            union { i32x4 i; bf16x8 v; } pu;
            pu.i = (i32x4){a0, a1, b0, b1};
            const bf16x8 pf = pu.v;

            // O^T += V P^T ; l += 1 P^T   (K-dim = 32 keys of this slice)
            __builtin_amdgcn_s_setprio(1);
#pragma unroll
            for (int dt = 0; dt < 4; ++dt)
                oacc[dt] = __builtin_amdgcn_mfma_f32_16x16x32_bf16(
                    vreg[kc][dt], pf, oacc[dt], 0, 0, 0);
            lacc = __builtin_amdgcn_mfma_f32_16x16x32_bf16(onesf, pf, lacc, 0, 0, 0);
            __builtin_amdgcn_s_setprio(0);
        }
        if (++cur >= 3) cur = 0;
    }

    // epilogue: O / l; lane owns q = lane&15, writes 4x 8B chunks along d
    const int b = bh >> 4, h = bh & 15;
    const float inv = 1.f / lacc[0];
    const int srow2 = qt * 64 + wave * 16 + row;
    __bf16* obase = att + ((size_t)b * S_ + srow2) * D_ + h * DH_;
#pragma unroll
    for (int dt = 0; dt < 4; ++dt) {
        bf16x4 o;
#pragma unroll
        for (int r = 0; r < 4; ++r) o[r] = (__bf16)(oacc[dt][r] * inv);
        *(bf16x4*)(obase + dt * 16 + quad * 4) = o;
    }
}

// ---- Output projection: out = att @ W_O^T + b_O (bf16 in, fp32 out) -------
__global__ void oproj_kernel(const __bf16* __restrict__ attn, const __bf16* __restrict__ wob,
                             const float* __restrict__ bo, float* __restrict__ out) {
    __shared__ __align__(16) __bf16 SMEM[24576];  // 48 KB: 3-buf As|Bs
    __bf16* As = SMEM;
    __bf16* Bs = SMEM + 12288;
    const int m0 = blockIdx.y * 128, n0 = blockIdx.x * 128;

    f32x4 acc[4][4];
    gemm128_bf(attn, wob, m0, n0, D_, As, Bs, acc);

    const int tid = threadIdx.x;
    const int wave = tid >> 6, lane = tid & 63;
    const int row = lane & 15, quad = lane >> 4;
    const int wm = wave >> 1, wn = wave & 1;

#pragma unroll
    for (int nt = 0; nt < 4; ++nt) {
        const int n = n0 + wn * 64 + nt * 16 + row;
        const float bf = bo[n];
#pragma unroll
        for (int mt = 0; mt < 4; ++mt) {
#pragma unroll
            for (int r = 0; r < 4; ++r) {
                const int m = m0 + wm * 64 + mt * 16 + quad * 4 + r;
                out[(size_t)m * D_ + n] = acc[mt][nt][r] + bf;
            }
        }
    }
}

extern "C" void kernel_launch(void* const* d_in, const int* in_sizes, int n_in,
                              void* d_out, int out_size, void* d_ws, size_t ws_size,
                              hipStream_t stream) {
    const float* q_in = (const float*)d_in[0];
    const float* k_in = (const float*)d_in[1];
    const float* v_in = (const float*)d_in[2];
    const float* wq   = (const float*)d_in[3];
    const float* bq   = (const float*)d_in[4];
    const float* wk   = (const float*)d_in[5];
    const float* bk   = (const float*)d_in[6];
    const float* wv   = (const float*)d_in[7];
    const float* bv   = (const float*)d_in[8];
    const float* wo   = (const float*)d_in[9];
    const float* bo   = (const float*)d_in[10];

    char* ws = (char*)d_ws;
    const size_t MB = 1024 * 1024;
    __bf16* qb   = (__bf16*)(ws);            // 8 MB
    __bf16* kb   = (__bf16*)(ws + 8 * MB);   // 8 MB
    __bf16* vb   = (__bf16*)(ws + 16 * MB);  // 8 MB
    __bf16* wqb  = (__bf16*)(ws + 24 * MB);  // 2 MB
    __bf16* wkb  = (__bf16*)(ws + 26 * MB);  // 2 MB
    __bf16* wvb  = (__bf16*)(ws + 28 * MB);  // 2 MB
    __bf16* wob  = (__bf16*)(ws + 30 * MB);  // 2 MB
    __bf16* q_ws = (__bf16*)(ws + 32 * MB);  // 8 MB
    __bf16* k_ws = (__bf16*)(ws + 40 * MB);  // 8 MB
    __bf16* v_ws = (__bf16*)(ws + 48 * MB);  // 8 MB  (total 56 MB)
    __bf16* attb = qb;                       // alias: qb dead after qkv_kernel
    float*  out  = (float*)d_out;

    cvt_kernel<<<dim3(2048, 1, 7), 256, 0, stream>>>(
        q_in, k_in, v_in, wq, wk, wv, wo, qb, kb, vb, wqb, wkb, wvb, wob);
    qkv_kernel<<<dim3(D_ / 128, (B_ * S_) / 128, 3), 256, 0, stream>>>(
        qb, kb, vb, wqb, wkb, wvb, bq, bk, bv, q_ws, k_ws, v_ws);
    attn_kernel<<<dim3(32 * 32), 256, 0, stream>>>(q_ws, k_ws, v_ws, attb);
    oproj_kernel<<<dim3(D_ / 128, (B_ * S_) / 128), 256, 0, stream>>>(attb, wob, bo, out);
}

// Round 10
// 201.011 us; speedup vs baseline: 1.2396x; 1.2396x over previous
//
#include <hip/hip_runtime.h>

// MultiHeadedAttention: B=2, S=2048, D=1024, H=16, DH=64.
// fp32 in/out; internal bf16 MFMA pipeline.
// cvt (fp32->bf16) -> QKV bf16 GEMMs -> flash attention (static-max) -> oproj.
// R1: attn 4 blocks/CU, XOR-swizzled LDS, setprio.
// R2: 2-phase double-buffer (one barrier/tile).
// R4: V epilogue via LDS transpose -> 16B stores.
// R5: swapped QK^T + in-register P redistribution (permlane32/16); conflicts=0.
// R6: paired q-tiles REGRESSED (resident-wave starvation) -> reverted.
// R7: fused fp32 reg-staging REGRESSED (scratch spills) -> reverted.
// R8: GEMM core -> 3-buffer depth-2 prefetch, counted vmcnt(4) + raw barrier
//     (qkv 47.8->41.6). attn: -M2 folded into S-acc init.
// R9: attn direct-global V REGRESSED (V latency moved onto the per-tile
//     critical path; 41.5->82.7) -> attn reverted to R8 form.
// R10: qkv/oproj grid axes swapped (x = m-panel): XCD = m&7, so each XCD's 4
//     A-panels (1MB/mode) stay L2-resident across the n sweep -> A fetched
//     once, not 8x (predicted FETCH 101->~72MB). Pure decode swap, no
//     occupancy/LDS/store changes.

typedef __bf16 bf16x8 __attribute__((ext_vector_type(8)));
typedef __bf16 bf16x4 __attribute__((ext_vector_type(4)));
typedef float  f32x4  __attribute__((ext_vector_type(4)));
typedef int    i32x2  __attribute__((ext_vector_type(2)));
typedef int    i32x4  __attribute__((ext_vector_type(4)));

#define B_  2
#define S_  2048
#define D_  1024
#define H_  16
#define DH_ 64

#define NEG_ 1.0e30f              // finite "-inf": exp2 -> 0, no inf-inf NaN
#define M2_  5.77078016f          // static softmax max: 4.0 * log2(e)
#define QSCALE_ 0.18033688f       // 1/sqrt(64) * log2(e): scores in log2 domain

#if __has_builtin(__builtin_amdgcn_exp2f)
#define EXP2(x) __builtin_amdgcn_exp2f(x)
#else
#define EXP2(x) __builtin_exp2f(x)
#endif

// ---- async 16B global -> LDS copy (lane l writes lds_base + l*16B) ---------
__device__ __forceinline__ void load_lds16(const __bf16* g, __bf16* lds_base) {
    __builtin_amdgcn_global_load_lds(
        (const __attribute__((address_space(1))) void*)g,
        (__attribute__((address_space(3))) void*)lds_base,
        16, 0, 0);
}

// ---- pack two f32 -> one u32 of 2 bf16 (lo = first) ------------------------
__device__ __forceinline__ int pack_bf16(float lo, float hi) {
    union { int u; __bf16 h[2]; } r;
    r.h[0] = (__bf16)lo; r.h[1] = (__bf16)hi;
    return r.u;
}

// ---- cross-lane half swaps (32-lane and 16-lane rows) ----------------------
__device__ __forceinline__ void p32swap(int& a, int& b, int lane) {
#if __has_builtin(__builtin_amdgcn_permlane32_swap)
    i32x2 r = __builtin_amdgcn_permlane32_swap(a, b, false, false);
    a = r[0]; b = r[1];
#else
    const int addr = ((lane ^ 32) & 63) << 2;
    int ax = __builtin_amdgcn_ds_bpermute(addr, a);
    int bx = __builtin_amdgcn_ds_bpermute(addr, b);
    int na = (lane < 32) ? a : bx;
    int nb = (lane < 32) ? ax : b;
    a = na; b = nb;
#endif
}
__device__ __forceinline__ void p16swap(int& a, int& b, int lane) {
#if __has_builtin(__builtin_amdgcn_permlane16_swap)
    i32x2 r = __builtin_amdgcn_permlane16_swap(a, b, false, false);
    a = r[0]; b = r[1];
#else
    int as = __builtin_amdgcn_ds_swizzle(a, 0x401F);  // lane ^ 16 (in 32-grp)
    int bs = __builtin_amdgcn_ds_swizzle(b, 0x401F);
    const bool odd = (lane >> 4) & 1;
    int na = odd ? bs : a;
    int nb = odd ? b : as;
    a = na; b = nb;
#endif
}

// ---- load 8 consecutive fp32, convert to packed bf16x8 ---------------------
__device__ __forceinline__ bf16x8 cvt8(const float* __restrict__ p) {
    const float4 a = *(const float4*)p;
    const float4 b = *(const float4*)(p + 4);
    bf16x8 r;
    r[0] = (__bf16)a.x; r[1] = (__bf16)a.y; r[2] = (__bf16)a.z; r[3] = (__bf16)a.w;
    r[4] = (__bf16)b.x; r[5] = (__bf16)b.y; r[6] = (__bf16)b.z; r[7] = (__bf16)b.w;
    return r;
}

// ---- fp32 -> bf16 conversion pass: z picks tensor --------------------------
__global__ void cvt_kernel(const float* __restrict__ q, const float* __restrict__ k,
                           const float* __restrict__ v,
                           const float* __restrict__ wq, const float* __restrict__ wk,
                           const float* __restrict__ wv, const float* __restrict__ wo,
                           __bf16* __restrict__ qb, __bf16* __restrict__ kb,
                           __bf16* __restrict__ vb,
                           __bf16* __restrict__ wqb, __bf16* __restrict__ wkb,
                           __bf16* __restrict__ wvb, __bf16* __restrict__ wob) {
    const int z = blockIdx.z;
    const float* src; __bf16* dst; size_t n;
    switch (z) {
        case 0: src = q;  dst = qb;  n = (size_t)B_ * S_ * D_; break;
        case 1: src = k;  dst = kb;  n = (size_t)B_ * S_ * D_; break;
        case 2: src = v;  dst = vb;  n = (size_t)B_ * S_ * D_; break;
        case 3: src = wq; dst = wqb; n = (size_t)D_ * D_; break;
        case 4: src = wk; dst = wkb; n = (size_t)D_ * D_; break;
        case 5: src = wv; dst = wvb; n = (size_t)D_ * D_; break;
        default: src = wo; dst = wob; n = (size_t)D_ * D_; break;
    }
    const size_t i = ((size_t)blockIdx.x * 256 + threadIdx.x) * 8;
    if (i >= n) return;
    *(bf16x8*)(dst + i) = cvt8(src + i);
}

// ---- 128x128 bf16 GEMM core, 3-buffer depth-2 prefetch, counted vmcnt ------
// Y[m,n] = sum_k X[m,k]*W[n,k]. As/Bs are [3][128*32] bf16 (each op 24KB).
// Per K-step: s_waitcnt vmcnt(4) (own stage(k) loads only; stage(k+1) stays
// in flight) -> s_barrier -> issue stage(k+2) -> ds_read + 16 MFMA.
__device__ __forceinline__ void gemm128_bf(const __bf16* __restrict__ X,
                                           const __bf16* __restrict__ W,
                                           int m0, int n0, int K,
                                           __bf16* As, __bf16* Bs,
                                           f32x4 acc[4][4]) {
    const int tid  = threadIdx.x;
    const int wave = tid >> 6, lane = tid & 63;
    const int row  = lane & 15, quad = lane >> 4;
    const int wm   = wave >> 1, wn = wave & 1;
    const int arow = lane >> 2;        // 0..15 row within 16-row chunk
    const int acol = (lane & 3) * 8;   // elem offset within 32-elem row

    const f32x4 fzero = {0.f, 0.f, 0.f, 0.f};
#pragma unroll
    for (int mt = 0; mt < 4; ++mt)
#pragma unroll
        for (int nt = 0; nt < 4; ++nt) acc[mt][nt] = fzero;

    auto stage = [&](int buf, int k0) {   // 4 global_load_lds per wave
#pragma unroll
        for (int c = 0; c < 2; ++c) {
            const int j = wave * 2 + c;  // chunk 0..7, 16 rows each
            load_lds16(X + (size_t)(m0 + j * 16 + arow) * K + k0 + acol,
                       As + buf * 4096 + j * 512);
            load_lds16(W + (size_t)(n0 + j * 16 + arow) * K + k0 + acol,
                       Bs + buf * 4096 + j * 512);
        }
    };

    stage(0, 0);
    if (K > 32) stage(1, 32);
    int cur = 0;
    for (int k0 = 0; k0 < K; k0 += 32) {
        // wait own stage(k) (oldest 4); stage(k+1)'s 4 may stay in flight
        if (k0 + 32 < K) asm volatile("s_waitcnt vmcnt(4)" ::: "memory");
        else             asm volatile("s_waitcnt vmcnt(0)" ::: "memory");
        __builtin_amdgcn_s_barrier();
        __builtin_amdgcn_sched_barrier(0);
        if (k0 + 64 < K) {
            int nxt2 = cur + 2; if (nxt2 >= 3) nxt2 -= 3;
            stage(nxt2, k0 + 64);          // depth-2 prefetch, issued early
        }
        const __bf16* Ab = As + cur * 4096;
        const __bf16* Bb = Bs + cur * 4096;
        bf16x8 af[4], bfv[4];
#pragma unroll
        for (int t = 0; t < 4; ++t) {
            af[t]  = *(const bf16x8*)(Ab + (wm * 64 + t * 16 + row) * 32 + quad * 8);
            bfv[t] = *(const bf16x8*)(Bb + (wn * 64 + t * 16 + row) * 32 + quad * 8);
        }
        __builtin_amdgcn_s_setprio(1);
#pragma unroll
        for (int mt = 0; mt < 4; ++mt)
#pragma unroll
            for (int nt = 0; nt < 4; ++nt)
                acc[mt][nt] = __builtin_amdgcn_mfma_f32_16x16x32_bf16(
                    af[mt], bfv[nt], acc[mt][nt], 0, 0, 0);
        __builtin_amdgcn_s_setprio(0);
        if (++cur >= 3) cur = 0;
    }
    // all staging drained (last iter waited vmcnt(0)); barrier before any
    // LDS reuse by caller epilogues:
    __builtin_amdgcn_s_barrier();
}

// ---- QKV projection (bf16): z selects Q/K/V. Head-split layouts. ----------
// R10 grid: x = m-panel (32), y = n-panel (8) -> XCD = m&7 keeps each XCD's
// 4 A-panels L2-resident across the n sweep (A fetched once, not 8x).
__global__ void qkv_kernel(const __bf16* __restrict__ qb, const __bf16* __restrict__ kb,
                           const __bf16* __restrict__ vb,
                           const __bf16* __restrict__ wqb, const __bf16* __restrict__ wkb,
                           const __bf16* __restrict__ wvb,
                           const float* __restrict__ bq, const float* __restrict__ bk,
                           const float* __restrict__ bv,
                           __bf16* __restrict__ q_ws, __bf16* __restrict__ k_ws,
                           __bf16* __restrict__ v_ws) {
    __shared__ __align__(16) __bf16 SMEM[24576];  // 48 KB: 3-buf As|Bs, then V-transpose
    __bf16* As = SMEM;
    __bf16* Bs = SMEM + 12288;

    const int mode = blockIdx.z;
    const __bf16* X    = mode == 0 ? qb : mode == 1 ? kb : vb;
    const __bf16* W    = mode == 0 ? wqb : mode == 1 ? wkb : wvb;
    const float*  bias = mode == 0 ? bq : mode == 1 ? bk : bv;
    const int m0 = blockIdx.x * 128, n0 = blockIdx.y * 128;  // R10: x=m, y=n

    f32x4 acc[4][4];
    gemm128_bf(X, W, m0, n0, D_, As, Bs, acc);

    const int tid = threadIdx.x;
    const int wave = tid >> 6, lane = tid & 63;
    const int row = lane & 15, quad = lane >> 4;
    const int wm = wave >> 1, wn = wave & 1;

    if (mode == 2) {
        // ---- V path: LDS transpose -> vectorized stores along s ----
        __bf16* T = SMEM;              // [nloc][mloc], 16B-chunk XOR swizzle
#pragma unroll
        for (int nt = 0; nt < 4; ++nt) {
            const int nloc = wn * 64 + nt * 16 + row;
            const float bf = bias[n0 + nloc];
#pragma unroll
            for (int mt = 0; mt < 4; ++mt)
#pragma unroll
                for (int r2 = 0; r2 < 4; ++r2) {
                    const int mloc = wm * 64 + mt * 16 + quad * 4 + r2;
                    T[nloc * 128 + ((((mloc >> 3) ^ (nloc & 15)) << 3) | (mloc & 7))] =
                        (__bf16)(acc[mt][nt][r2] + bf);
                }
        }
        __syncthreads();
#pragma unroll
        for (int p = 0; p < 8; ++p) {
            const int nloc = p * 16 + (tid >> 4);
            const int k = tid & 15;    // m-chunk index (8 consecutive s)
            bf16x8 vv = *(const bf16x8*)(T + nloc * 128 + ((k ^ (nloc & 15)) << 3));
            const int n = n0 + nloc;
            const int h = n >> 6, dh = n & 63;
            const int m = m0 + k * 8;
            const int bb = m >> 11, s = m & (S_ - 1);
            *(bf16x8*)(v_ws + (((size_t)bb * H_ + h) * DH_ + dh) * S_ + s) = vv;
        }
        return;
    }

    // ---- Q/K path: direct stores (32B runs per quad, acceptable) ----
#pragma unroll
    for (int nt = 0; nt < 4; ++nt) {
        const int n  = n0 + wn * 64 + nt * 16 + row;
        const float bf = bias[n];
        const int h = n >> 6, dh = n & 63;
#pragma unroll
        for (int mt = 0; mt < 4; ++mt) {
#pragma unroll
            for (int r2 = 0; r2 < 4; ++r2) {
                const int m = m0 + wm * 64 + mt * 16 + quad * 4 + r2;
                const int bb = m >> 11, s = m & (S_ - 1);
                const float val = acc[mt][nt][r2] + bf;
                if (mode == 0)       // Q: (B,H,S,DH), scaled to log2 domain
                    q_ws[(((size_t)bb * H_ + h) * S_ + s) * DH_ + dh] = (__bf16)(val * QSCALE_);
                else                 // K: (B,H,S,DH)
                    k_ws[(((size_t)bb * H_ + h) * S_ + s) * DH_ + dh] = (__bf16)val;
            }
        }
    }
}

// ---- Flash attention (R8-proven): QBLK=64, KVBLK=64, 2-buffer K+V,
// one barrier/tile; swapped QK^T -> P^T in-register redistribution;
// S-acc init = -M2. LDS 32 KB -> 4 WG/CU.
__global__ __launch_bounds__(256, 4)
void attn_kernel(const __bf16* __restrict__ q_ws, const __bf16* __restrict__ k_ws,
                 const __bf16* __restrict__ v_ws, __bf16* __restrict__ att) {
    __shared__ __align__(16) __bf16 Ks[2 * 64 * 64];  // [key][dh], swizzled
    __shared__ __align__(16) __bf16 Vs[2 * 64 * 64];  // [dh][key], swizzled

    // XCD-aware decode: id%8 = XCD; each XCD owns 4 heads (2MB K/V -> L2-fit).
    const int id = blockIdx.x;
    const int bh = (id & 7) * 4 + ((id >> 3) & 3);
    const int u = id >> 5, ua = u >> 3, uj = u & 7;
    const int qt = ua * 8 + ((ua & 1) ? (7 - uj) : uj);  // balanced involution
    const int tid = threadIdx.x, wave = tid >> 6, lane = tid & 63;
    const int row = lane & 15, quad = lane >> 4;

    const __bf16* Qg = q_ws + ((size_t)bh * S_ + qt * 64 + wave * 16) * DH_;
    const __bf16* Kg = k_ws + (size_t)bh * S_ * DH_;
    const __bf16* Vg = v_ws + (size_t)bh * DH_ * S_;

    // Q fragments (B-operand): q-rows = lane&15, k = ks*32 + quad*8 .. +7
    bf16x8 qf[2];
#pragma unroll
    for (int ks = 0; ks < 2; ++ks)
        qf[ks] = *(const bf16x8*)(Qg + row * DH_ + ks * 32 + quad * 8);

    // all-ones A fragment for row-sum via MFMA: l[q] broadcast over rows
    bf16x8 onesf;
#pragma unroll
    for (int i = 0; i < 8; ++i) onesf[i] = (__bf16)1.0f;

    const f32x4 fzero = {0.f, 0.f, 0.f, 0.f};
    const f32x4 m2init = {-M2_, -M2_, -M2_, -M2_};
    f32x4 oacc[4];   // O^T accumulator: q = lane&15, d = dt*16 + quad*4 + r
    f32x4 lacc = fzero;
#pragma unroll
    for (int dt = 0; dt < 4; ++dt) oacc[dt] = fzero;

    // staging swizzle: LDS dest linear, global source pre-swizzled
    const int srow = lane >> 3;                  // row & 7 within chunk
    const int scol = ((lane & 7) ^ srow) * 8;    // pre-swizzled col (elems)
    const int nkv = qt + 1;

    auto stage = [&](int buf, int kv) {
        __bf16* Kd = Ks + buf * 4096;
        __bf16* Vd = Vs + buf * 4096;
#pragma unroll
        for (int c = 0; c < 2; ++c) {
            const int ck = wave * 2 + c;         // chunk 0..7, 8 rows each
            load_lds16(Kg + (size_t)(kv * 64 + ck * 8 + srow) * DH_ + scol, Kd + ck * 512);
            load_lds16(Vg + (size_t)(ck * 8 + srow) * S_ + kv * 64 + scol, Vd + ck * 512);
        }
    };

    stage(0, 0);
    int cur = 0;
    for (int kv = 0; kv < nkv; ++kv) {
        __syncthreads();                         // tile kv staged (vmcnt0 drain)
        if (kv + 1 < nkv) stage(cur ^ 1, kv + 1);  // prefetch under compute
        const bool diag = (kv == nkv - 1);
        const __bf16* Kb = Ks + cur * 4096;
        const __bf16* Vb = Vs + cur * 4096;
        const int swz = (row & 7) << 3;          // read-side XOR (elements)

        // process 64 keys in two 32-key slices: QK^T -> exp -> shuffle -> PV
#pragma unroll
        for (int kc = 0; kc < 2; ++kc) {
            // S^T slice = K Q^T: rows = keys (quad*4+r per jn), cols = q rows
            f32x4 s[2];
            s[0] = m2init; s[1] = m2init;        // -M2 folded into C-init
            __builtin_amdgcn_s_setprio(1);
#pragma unroll
            for (int jn = 0; jn < 2; ++jn) {
                const int nt = kc * 2 + jn;
                const int kb = (nt * 16 + row) * 64 + quad * 8;
                bf16x8 kf0 = *(const bf16x8*)(Kb + (kb ^ swz));
                bf16x8 kf1 = *(const bf16x8*)(Kb + ((kb + 32) ^ swz));
                s[jn] = __builtin_amdgcn_mfma_f32_16x16x32_bf16(kf0, qf[0], s[jn], 0, 0, 0);
                s[jn] = __builtin_amdgcn_mfma_f32_16x16x32_bf16(kf1, qf[1], s[jn], 0, 0, 0);
            }
            __builtin_amdgcn_s_setprio(0);

            if (diag) {  // causal mask: key_loc > q_loc -> masked
                const int rloc = wave * 16 + row;          // q row
#pragma unroll
                for (int jn = 0; jn < 2; ++jn)
#pragma unroll
                    for (int r = 0; r < 4; ++r) {
                        const int cloc = kc * 32 + jn * 16 + quad * 4 + r;  // key
                        if (cloc > rloc) s[jn][r] = -NEG_;
                    }
            }

            // p = 2^s (s already has -M2); pack; cross-lane to PV B-fragment
            float p0[4], p1[4];
#pragma unroll
            for (int r = 0; r < 4; ++r) {
                p0[r] = EXP2(s[0][r]);
                p1[r] = EXP2(s[1][r]);
            }
            int a0 = pack_bf16(p0[0], p0[1]), a1 = pack_bf16(p0[2], p0[3]);
            int b0 = pack_bf16(p1[0], p1[1]), b1 = pack_bf16(p1[2], p1[3]);
            p32swap(a0, b0, lane); p16swap(a0, b0, lane);  // -> Bfrag[0], Bfrag[2]
            p32swap(a1, b1, lane); p16swap(a1, b1, lane);  // -> Bfrag[1], Bfrag[3]
            union { i32x4 i; bf16x8 v; } pu;
            pu.i = (i32x4){a0, a1, b0, b1};
            const bf16x8 pf = pu.v;

            // O^T += V P^T ; l += 1 P^T   (K-dim = 32 keys of this slice)
            __builtin_amdgcn_s_setprio(1);
#pragma unroll
            for (int dt = 0; dt < 4; ++dt) {
                const int vb = (dt * 16 + row) * 64 + kc * 32 + quad * 8;
                bf16x8 vf = *(const bf16x8*)(Vb + (vb ^ swz));
                oacc[dt] = __builtin_amdgcn_mfma_f32_16x16x32_bf16(vf, pf, oacc[dt], 0, 0, 0);
            }
            lacc = __builtin_amdgcn_mfma_f32_16x16x32_bf16(onesf, pf, lacc, 0, 0, 0);
            __builtin_amdgcn_s_setprio(0);
        }
        cur ^= 1;
    }

    // epilogue: O / l; lane owns q = lane&15, writes 4x 8B chunks along d
    const int b = bh >> 4, h = bh & 15;
    const float inv = 1.f / lacc[0];
    const int srow2 = qt * 64 + wave * 16 + row;
    __bf16* obase = att + ((size_t)b * S_ + srow2) * D_ + h * DH_;
#pragma unroll
    for (int dt = 0; dt < 4; ++dt) {
        bf16x4 o;
#pragma unroll
        for (int r = 0; r < 4; ++r) o[r] = (__bf16)(oacc[dt][r] * inv);
        *(bf16x4*)(obase + dt * 16 + quad * 4) = o;
    }
}

// ---- Output projection: out = att @ W_O^T + b_O (bf16 in, fp32 out) -------
// R10 grid: x = m-panel (32), y = n-panel (8) -> A-panels XCD-resident.
__global__ void oproj_kernel(const __bf16* __restrict__ attn, const __bf16* __restrict__ wob,
                             const float* __restrict__ bo, float* __restrict__ out) {
    __shared__ __align__(16) __bf16 SMEM[24576];  // 48 KB: 3-buf As|Bs
    __bf16* As = SMEM;
    __bf16* Bs = SMEM + 12288;
    const int m0 = blockIdx.x * 128, n0 = blockIdx.y * 128;  // R10: x=m, y=n

    f32x4 acc[4][4];
    gemm128_bf(attn, wob, m0, n0, D_, As, Bs, acc);

    const int tid = threadIdx.x;
    const int wave = tid >> 6, lane = tid & 63;
    const int row = lane & 15, quad = lane >> 4;
    const int wm = wave >> 1, wn = wave & 1;

#pragma unroll
    for (int nt = 0; nt < 4; ++nt) {
        const int n = n0 + wn * 64 + nt * 16 + row;
        const float bf = bo[n];
#pragma unroll
        for (int mt = 0; mt < 4; ++mt) {
#pragma unroll
            for (int r = 0; r < 4; ++r) {
                const int m = m0 + wm * 64 + mt * 16 + quad * 4 + r;
                out[(size_t)m * D_ + n] = acc[mt][nt][r] + bf;
            }
        }
    }
}

extern "C" void kernel_launch(void* const* d_in, const int* in_sizes, int n_in,
                              void* d_out, int out_size, void* d_ws, size_t ws_size,
                              hipStream_t stream) {
    const float* q_in = (const float*)d_in[0];
    const float* k_in = (const float*)d_in[1];
    const float* v_in = (const float*)d_in[2];
    const float* wq   = (const float*)d_in[3];
    const float* bq   = (const float*)d_in[4];
    const float* wk   = (const float*)d_in[5];
    const float* bk   = (const float*)d_in[6];
    const float* wv   = (const float*)d_in[7];
    const float* bv   = (const float*)d_in[8];
    const float* wo   = (const float*)d_in[9];
    const float* bo   = (const float*)d_in[10];

    char* ws = (char*)d_ws;
    const size_t MB = 1024 * 1024;
    __bf16* qb   = (__bf16*)(ws);            // 8 MB
    __bf16* kb   = (__bf16*)(ws + 8 * MB);   // 8 MB
    __bf16* vb   = (__bf16*)(ws + 16 * MB);  // 8 MB
    __bf16* wqb  = (__bf16*)(ws + 24 * MB);  // 2 MB
    __bf16* wkb  = (__bf16*)(ws + 26 * MB);  // 2 MB
    __bf16* wvb  = (__bf16*)(ws + 28 * MB);  // 2 MB
    __bf16* wob  = (__bf16*)(ws + 30 * MB);  // 2 MB
    __bf16* q_ws = (__bf16*)(ws + 32 * MB);  // 8 MB
    __bf16* k_ws = (__bf16*)(ws + 40 * MB);  // 8 MB
    __bf16* v_ws = (__bf16*)(ws + 48 * MB);  // 8 MB  (total 56 MB)
    __bf16* attb = qb;                       // alias: qb dead after qkv_kernel
    float*  out  = (float*)d_out;

    cvt_kernel<<<dim3(2048, 1, 7), 256, 0, stream>>>(
        q_in, k_in, v_in, wq, wk, wv, wo, qb, kb, vb, wqb, wkb, wvb, wob);
    qkv_kernel<<<dim3((B_ * S_) / 128, D_ / 128, 3), 256, 0, stream>>>(
        qb, kb, vb, wqb, wkb, wvb, bq, bk, bv, q_ws, k_ws, v_ws);
    attn_kernel<<<dim3(32 * 32), 256, 0, stream>>>(q_ws, k_ws, v_ws, attb);
    oproj_kernel<<<dim3((B_ * S_) / 128, D_ / 128), 256, 0, stream>>>(attb, wob, bo, out);
}